// Round 6
// baseline (320.463 us; speedup 1.0000x reference)
//
#include <hip/hip_runtime.h>

#define DD 128
#define AA 64
#define SS 160   // fused sub-row stride in floats: 32 (64 bf16 logit) + 128 (f32 message)

static inline int idiv_up(int a, int b) { return (a + b - 1) / b; }

__device__ __forceinline__ unsigned short f2bf(float f) {
    unsigned u = __float_as_uint(f);
    u += 0x7fff + ((u >> 16) & 1);          // round-to-nearest-even
    return (unsigned short)(u >> 16);
}
__device__ __forceinline__ float bf2f(unsigned short h) {
    return __uint_as_float(((unsigned)h) << 16);
}

// ---------------------------------------------------------------------------
// Fused projections + edge histogram in ONE dispatch.
// Even bids: projection tiles (type 0: hidden -> subrows[logit bf16 | msg f32];
//   type 1: rela -> hrWr + relaWh; type 2: rela[q_rel] -> hqrWqr (+bqr)).
// Odd bids: histogram chunks (1024 edges each) -> deg[] atomics.
// Interleaving odd/even lets the memory-light histogram overlap the GEMM tiles.
// ---------------------------------------------------------------------------
__global__ __launch_bounds__(256)
void proj_hist_kernel(const float* __restrict__ hidden,
                      const float* __restrict__ rela,
                      const int* __restrict__ q_rel,
                      const float* __restrict__ Ws,
                      const float* __restrict__ Wr,
                      const float* __restrict__ Wqr,
                      const float* __restrict__ bqr,
                      const float* __restrict__ Wh,
                      const int* __restrict__ edges,
                      int* __restrict__ deg,
                      float* __restrict__ subrows,
                      float* __restrict__ hrWr,
                      float* __restrict__ relaWh,
                      float* __restrict__ hqrWqr,
                      int N, int NR, int B, int E,
                      int nA, int nB, int nC, int nH) {
    __shared__ float lht[128 * 64];    // transposed source tile [d][row]
    __shared__ float wbuf[128 * 64];   // current weight phase [d][c]
    const int t = threadIdx.x;
    const int bid = blockIdx.x;

    if (bid & 1) {
        // ---- histogram chunk ----
        const int hb = bid >> 1;
        if (hb >= nH) return;
        const int ebase = hb * 1024;
        #pragma unroll
        for (int j = 0; j < 4; ++j) {
            const int e = ebase + j * 256 + t;
            if (e < E) atomicAdd(&deg[edges[(long)e * 6 + 5]], 1);
        }
        return;
    }

    const int pb = bid >> 1;
    if (pb >= nA + nB + nC) return;
    int type, rbase, nrows;
    const float* src;
    if (pb < nA)           { type = 0; rbase = pb * 64;             nrows = N;  src = hidden; }
    else if (pb < nA + nB) { type = 1; rbase = (pb - nA) * 64;      nrows = NR; src = rela; }
    else                   { type = 2; rbase = (pb - nA - nB) * 64; nrows = B;  src = rela; }

    // stage source tile (transposed)
    const int row = t & 63;
    const int d0 = (t >> 6) * 32;
    const int gr = rbase + row;
    const float* srow = nullptr;
    if (gr < nrows) {
        const int sr = (type == 2) ? q_rel[gr] : gr;
        srow = src + (long)sr * DD;
    }
    #pragma unroll
    for (int j = 0; j < 8; ++j) {
        float4 v = make_float4(0.f, 0.f, 0.f, 0.f);
        if (srow) v = *(const float4*)&srow[d0 + j * 4];
        lht[(d0 + j * 4 + 0) * 64 + row] = v.x;
        lht[(d0 + j * 4 + 1) * 64 + row] = v.y;
        lht[(d0 + j * 4 + 2) * 64 + row] = v.z;
        lht[(d0 + j * 4 + 3) * 64 + row] = v.w;
    }

    const int r0 = (t & 15) * 4;
    const int c0 = (t >> 4) * 4;
    const int nph = (type == 2) ? 1 : 3;

    for (int p = 0; p < nph; ++p) {
        const float* W;
        int ldw, off;
        if (p == 0) {
            W = (type == 0) ? Ws : (type == 1) ? Wr : Wqr;
            ldw = 64; off = 0;
        } else {
            W = Wh; ldw = 128; off = (p - 1) * 64;
        }
        #pragma unroll
        for (int k = 0; k < 8192; k += 1024) {
            const int f = k + t * 4;
            *(float4*)&wbuf[f] = *(const float4*)&W[(long)(f >> 6) * ldw + off + (f & 63)];
        }
        __syncthreads();

        float acc[4][4] = {};
        #pragma unroll 4
        for (int d = 0; d < 128; ++d) {
            const float4 hv = *(const float4*)&lht[d * 64 + r0];
            const float4 wv = *(const float4*)&wbuf[d * 64 + c0];
            acc[0][0] = fmaf(hv.x, wv.x, acc[0][0]);
            acc[0][1] = fmaf(hv.x, wv.y, acc[0][1]);
            acc[0][2] = fmaf(hv.x, wv.z, acc[0][2]);
            acc[0][3] = fmaf(hv.x, wv.w, acc[0][3]);
            acc[1][0] = fmaf(hv.y, wv.x, acc[1][0]);
            acc[1][1] = fmaf(hv.y, wv.y, acc[1][1]);
            acc[1][2] = fmaf(hv.y, wv.z, acc[1][2]);
            acc[1][3] = fmaf(hv.y, wv.w, acc[1][3]);
            acc[2][0] = fmaf(hv.z, wv.x, acc[2][0]);
            acc[2][1] = fmaf(hv.z, wv.y, acc[2][1]);
            acc[2][2] = fmaf(hv.z, wv.z, acc[2][2]);
            acc[2][3] = fmaf(hv.z, wv.w, acc[2][3]);
            acc[3][0] = fmaf(hv.w, wv.x, acc[3][0]);
            acc[3][1] = fmaf(hv.w, wv.y, acc[3][1]);
            acc[3][2] = fmaf(hv.w, wv.z, acc[3][2]);
            acc[3][3] = fmaf(hv.w, wv.w, acc[3][3]);
        }

        #pragma unroll
        for (int i = 0; i < 4; ++i) {
            const int orow = rbase + r0 + i;
            if (orow >= nrows) continue;
            if (type == 0) {
                float* srw = subrows + (long)orow * SS;
                if (p == 0) {
                    ushort4 o;
                    o.x = f2bf(acc[i][0]); o.y = f2bf(acc[i][1]);
                    o.z = f2bf(acc[i][2]); o.w = f2bf(acc[i][3]);
                    *(ushort4*)((unsigned short*)srw + c0) = o;
                } else {
                    *(float4*)(srw + 32 + off + c0) =
                        make_float4(acc[i][0], acc[i][1], acc[i][2], acc[i][3]);
                }
            } else if (type == 1) {
                if (p == 0) {
                    *(float4*)&hrWr[(long)orow * 64 + c0] =
                        make_float4(acc[i][0], acc[i][1], acc[i][2], acc[i][3]);
                } else {
                    *(float4*)&relaWh[(long)orow * 128 + off + c0] =
                        make_float4(acc[i][0], acc[i][1], acc[i][2], acc[i][3]);
                }
            } else {
                const float4 bq = *(const float4*)&bqr[c0];
                *(float4*)&hqrWqr[(long)orow * 64 + c0] =
                    make_float4(acc[i][0] + bq.x, acc[i][1] + bq.y,
                                acc[i][2] + bq.z, acc[i][3] + bq.w);
            }
        }
        __syncthreads();   // wbuf reused next phase
    }
}

// ---------------------------------------------------------------------------
// Single-block exclusive scan of deg[0..N) -> offs, seeds cur. 1024 threads,
// 4096 elems/chunk: wave shfl-scan + serial 16-wave combine.
// ---------------------------------------------------------------------------
__global__ __launch_bounds__(1024)
void scan_kernel(const int* __restrict__ deg, int* __restrict__ offs,
                 int* __restrict__ cur, int N) {
    __shared__ int wsum[17];
    const int t = threadIdx.x;
    const int lane = t & 63;
    const int wv = t >> 6;   // 0..15
    int carry = 0;
    for (int base = 0; base < N; base += 4096) {
        const int i0 = base + t * 4;
        int v0 = 0, v1 = 0, v2 = 0, v3 = 0;
        if (i0 + 3 < N) {
            const int4 q = *(const int4*)&deg[i0];
            v0 = q.x; v1 = q.y; v2 = q.z; v3 = q.w;
        } else {
            if (i0 + 0 < N) v0 = deg[i0 + 0];
            if (i0 + 1 < N) v1 = deg[i0 + 1];
            if (i0 + 2 < N) v2 = deg[i0 + 2];
            if (i0 + 3 < N) v3 = deg[i0 + 3];
        }
        const int s = v0 + v1 + v2 + v3;
        int inc = s;
        #pragma unroll
        for (int o = 1; o < 64; o <<= 1) {
            const int x = __shfl_up(inc, o, 64);
            if (lane >= o) inc += x;
        }
        if (lane == 63) wsum[wv] = inc;
        __syncthreads();
        if (t == 0) {
            int run = 0;
            #pragma unroll
            for (int k = 0; k < 16; ++k) { const int tmp = wsum[k]; wsum[k] = run; run += tmp; }
            wsum[16] = run;
        }
        __syncthreads();
        int e = carry + wsum[wv] + (inc - s);
        if (i0 + 0 < N) { offs[i0 + 0] = e; cur[i0 + 0] = e; } e += v0;
        if (i0 + 1 < N) { offs[i0 + 1] = e; cur[i0 + 1] = e; } e += v1;
        if (i0 + 2 < N) { offs[i0 + 2] = e; cur[i0 + 2] = e; } e += v2;
        if (i0 + 3 < N) { offs[i0 + 3] = e; cur[i0 + 3] = e; } e += v3;
        carry += wsum[16];
        __syncthreads();   // wsum reused next chunk
    }
}

// pack (sub, rel | ridx<<16) records bucketed by obj; cur pre-seeded with offs
__global__ void scatter_kernel(const int* __restrict__ edges, int* cur,
                               int2* __restrict__ recs, int E) {
    const int e = blockIdx.x * blockDim.x + threadIdx.x;
    if (e >= E) return;
    const int2 a = *(const int2*)&edges[(long)e * 6];      // ridx, _
    const int2 b = *(const int2*)&edges[(long)e * 6 + 2];  // rel, _
    const int2 c = *(const int2*)&edges[(long)e * 6 + 4];  // sub, obj
    const int pos = atomicAdd(&cur[c.y], 1);
    recs[pos] = make_int2(c.x, b.x | (a.x << 16));
}

// ---------------------------------------------------------------------------
// Gather: one wave per destination node, 16 lanes per edge, 8 edges in flight.
// out[v] = sum_e alpha_e * (hiddenWh[sub] + relaWh[rel]); msg part of subrows
// holds hiddenWh, logit part holds bf16 hsWs.
// ---------------------------------------------------------------------------
__global__ __launch_bounds__(256)
void gather_kernel(const int2* __restrict__ recs,
                   const int* __restrict__ offs,
                   const float* __restrict__ subrows,
                   const float* __restrict__ hrWr,
                   const float* __restrict__ hqrWqr,
                   const float* __restrict__ relaWh,
                   const float* __restrict__ wa,
                   const float* __restrict__ ba,
                   float* __restrict__ out, int N, int E) {
    const int lane = threadIdx.x & 63;
    const int g = lane >> 4;      // edge-group 0..3
    const int l = lane & 15;      // lane within group
    const int v = (int)((blockIdx.x * blockDim.x + threadIdx.x) >> 6);
    if (v >= N) return;
    const float4 wav = *(const float4*)&wa[l * 4];
    const float bar = ba[0];
    const int start = offs[v];
    const int end = (v + 1 < N) ? offs[v + 1] : E;

    float4 acc0 = make_float4(0.f, 0.f, 0.f, 0.f);
    float4 acc1 = make_float4(0.f, 0.f, 0.f, 0.f);

    for (int base = start; base < end; base += 8) {
        const int k1 = base + g;
        const int k2 = base + 4 + g;
        const bool va1 = (k1 < end);
        const bool va2 = (k2 < end);
        const int2 rc1 = va1 ? recs[k1] : make_int2(0, 0);
        const int2 rc2 = va2 ? recs[k2] : make_int2(0, 0);
        const int sub1 = rc1.x, rel1 = rc1.y & 0xffff, rid1 = rc1.y >> 16;
        const int sub2 = rc2.x, rel2 = rc2.y & 0xffff, rid2 = rc2.y >> 16;
        const float* sr1 = subrows + (long)sub1 * SS;
        const float* sr2 = subrows + (long)sub2 * SS;

        // issue all gathers up front (deep MLP)
        const ushort4 hw1 = *(const ushort4*)((const unsigned short*)sr1 + l * 4);
        const ushort4 hw2 = *(const ushort4*)((const unsigned short*)sr2 + l * 4);
        const float4 b41 = *(const float4*)&hrWr[rel1 * AA + l * 4];
        const float4 b42 = *(const float4*)&hrWr[rel2 * AA + l * 4];
        const float4 c41 = *(const float4*)&hqrWqr[rid1 * AA + l * 4];
        const float4 c42 = *(const float4*)&hqrWqr[rid2 * AA + l * 4];
        const float4 h01 = *(const float4*)(sr1 + 32 + l * 8);
        const float4 h11 = *(const float4*)(sr1 + 32 + l * 8 + 4);
        const float4 h02 = *(const float4*)(sr2 + 32 + l * 8);
        const float4 h12 = *(const float4*)(sr2 + 32 + l * 8 + 4);
        const float4 r01 = *(const float4*)&relaWh[rel1 * DD + l * 8];
        const float4 r11 = *(const float4*)&relaWh[rel1 * DD + l * 8 + 4];
        const float4 r02 = *(const float4*)&relaWh[rel2 * DD + l * 8];
        const float4 r12 = *(const float4*)&relaWh[rel2 * DD + l * 8 + 4];

        float s1 = fmaxf(bf2f(hw1.x) + b41.x + c41.x, 0.f) * wav.x;
        s1 = fmaf(fmaxf(bf2f(hw1.y) + b41.y + c41.y, 0.f), wav.y, s1);
        s1 = fmaf(fmaxf(bf2f(hw1.z) + b41.z + c41.z, 0.f), wav.z, s1);
        s1 = fmaf(fmaxf(bf2f(hw1.w) + b41.w + c41.w, 0.f), wav.w, s1);
        float s2 = fmaxf(bf2f(hw2.x) + b42.x + c42.x, 0.f) * wav.x;
        s2 = fmaf(fmaxf(bf2f(hw2.y) + b42.y + c42.y, 0.f), wav.y, s2);
        s2 = fmaf(fmaxf(bf2f(hw2.z) + b42.z + c42.z, 0.f), wav.z, s2);
        s2 = fmaf(fmaxf(bf2f(hw2.w) + b42.w + c42.w, 0.f), wav.w, s2);
        s1 += __shfl_xor(s1, 1);  s2 += __shfl_xor(s2, 1);
        s1 += __shfl_xor(s1, 2);  s2 += __shfl_xor(s2, 2);
        s1 += __shfl_xor(s1, 4);  s2 += __shfl_xor(s2, 4);
        s1 += __shfl_xor(s1, 8);  s2 += __shfl_xor(s2, 8);
        float al1 = __builtin_amdgcn_rcpf(1.0f + __expf(-(s1 + bar)));
        float al2 = __builtin_amdgcn_rcpf(1.0f + __expf(-(s2 + bar)));
        if (!va1) al1 = 0.0f;
        if (!va2) al2 = 0.0f;

        acc0.x = fmaf(al1, h01.x + r01.x, acc0.x);
        acc0.y = fmaf(al1, h01.y + r01.y, acc0.y);
        acc0.z = fmaf(al1, h01.z + r01.z, acc0.z);
        acc0.w = fmaf(al1, h01.w + r01.w, acc0.w);
        acc1.x = fmaf(al1, h11.x + r11.x, acc1.x);
        acc1.y = fmaf(al1, h11.y + r11.y, acc1.y);
        acc1.z = fmaf(al1, h11.z + r11.z, acc1.z);
        acc1.w = fmaf(al1, h11.w + r11.w, acc1.w);
        acc0.x = fmaf(al2, h02.x + r02.x, acc0.x);
        acc0.y = fmaf(al2, h02.y + r02.y, acc0.y);
        acc0.z = fmaf(al2, h02.z + r02.z, acc0.z);
        acc0.w = fmaf(al2, h02.w + r02.w, acc0.w);
        acc1.x = fmaf(al2, h12.x + r12.x, acc1.x);
        acc1.y = fmaf(al2, h12.y + r12.y, acc1.y);
        acc1.z = fmaf(al2, h12.z + r12.z, acc1.z);
        acc1.w = fmaf(al2, h12.w + r12.w, acc1.w);
    }

    // combine the 4 edge-groups
    #pragma unroll
    for (int o = 16; o <= 32; o <<= 1) {
        acc0.x += __shfl_xor(acc0.x, o);
        acc0.y += __shfl_xor(acc0.y, o);
        acc0.z += __shfl_xor(acc0.z, o);
        acc0.w += __shfl_xor(acc0.w, o);
        acc1.x += __shfl_xor(acc1.x, o);
        acc1.y += __shfl_xor(acc1.y, o);
        acc1.z += __shfl_xor(acc1.z, o);
        acc1.w += __shfl_xor(acc1.w, o);
    }
    if (g == 0) {
        *(float4*)&out[(long)v * DD + l * 8]     = acc0;
        *(float4*)&out[(long)v * DD + l * 8 + 4] = acc1;
    }
}

extern "C" void kernel_launch(void* const* d_in, const int* in_sizes, int n_in,
                              void* d_out, int out_size, void* d_ws, size_t ws_size,
                              hipStream_t stream) {
    // inputs: 0 q_sub (unused), 1 q_rel, 2 hidden, 3 edges, 4 n_node,
    //         5 rela_embed, 6 Ws, 7 Wr, 8 Wqr, 9 bqr, 10 wa, 11 ba, 12 Wh
    const int*   q_rel  = (const int*)d_in[1];
    const float* hidden = (const float*)d_in[2];
    const int*   edges  = (const int*)d_in[3];
    const float* rela   = (const float*)d_in[5];
    const float* Ws     = (const float*)d_in[6];
    const float* Wr     = (const float*)d_in[7];
    const float* Wqr    = (const float*)d_in[8];
    const float* bqr    = (const float*)d_in[9];
    const float* wa     = (const float*)d_in[10];
    const float* ba     = (const float*)d_in[11];
    const float* Wh     = (const float*)d_in[12];

    const int B  = in_sizes[1];
    const int N  = in_sizes[2] / DD;
    const int E  = in_sizes[3] / 6;
    const int NR = in_sizes[5] / DD;

    float* out = (float*)d_out;

    // workspace layout
    float* subrows = (float*)d_ws;                         // N x SS (bf16 logit + f32 msg)
    float* hrWr    = subrows + (size_t)N * SS;             // NR x 64
    float* relaWh  = hrWr + (size_t)NR * AA;               // NR x 128
    float* hqrWqr  = relaWh + (size_t)NR * DD;             // B x 64
    int*   deg     = (int*)(hqrWqr + (size_t)B * AA);      // N
    int*   cur     = deg  + N;                             // N
    int*   offs    = cur  + N;                             // N
    int2*  recs    = (int2*)(offs + N);                    // E

    const int nA = idiv_up(N, 64);
    const int nB = idiv_up(NR, 64);
    const int nC = idiv_up(B, 64);
    const int nH = idiv_up(E, 1024);
    const int nP = nA + nB + nC;
    const int grid_ph = 2 * ((nP > nH) ? nP : nH);

    hipMemsetAsync(deg, 0, (size_t)N * sizeof(int), stream);
    proj_hist_kernel<<<grid_ph, 256, 0, stream>>>(
        hidden, rela, q_rel, Ws, Wr, Wqr, bqr, Wh, edges, deg,
        subrows, hrWr, relaWh, hqrWqr, N, NR, B, E, nA, nB, nC, nH);
    scan_kernel<<<1, 1024, 0, stream>>>(deg, offs, cur, N);
    scatter_kernel<<<idiv_up(E, 256), 256, 0, stream>>>(edges, cur, recs, E);
    gather_kernel<<<idiv_up(N * 64, 256), 256, 0, stream>>>(
        recs, offs, subrows, hrWr, hqrWqr, relaWh, wa, ba, out, N, E);
}

// Round 7
// 289.508 us; speedup vs baseline: 1.1069x; 1.1069x over previous
//
#include <hip/hip_runtime.h>

#define DD 128
#define AA 64
#define SS 96    // fused sub-row stride in floats: 32 (64 bf16 logit) + 64 (128 bf16 msg)

static inline int idiv_up(int a, int b) { return (a + b - 1) / b; }

__device__ __forceinline__ unsigned short f2bf(float f) {
    unsigned u = __float_as_uint(f);
    u += 0x7fff + ((u >> 16) & 1);          // round-to-nearest-even
    return (unsigned short)(u >> 16);
}
__device__ __forceinline__ float bf2f(unsigned short h) {
    return __uint_as_float(((unsigned)h) << 16);
}

// ---------------------------------------------------------------------------
// Fused projections. 32KB LDS (source tile only); weight fragments read from
// global per-iteration (L1-resident broadcast: Ws/Wr/Wqr 32KB, Wh 64KB).
//  type 0: hidden -> subrows [64 bf16 logit | 128 bf16 msg]
//  type 1: rela   -> hrWr (f32) + relaWh (f32)
//  type 2: rela[q_rel] -> hqrWqr (f32, +bqr)
// ---------------------------------------------------------------------------
__global__ __launch_bounds__(256)
void proj_all_kernel(const float* __restrict__ hidden,
                     const float* __restrict__ rela,
                     const int* __restrict__ q_rel,
                     const float* __restrict__ Ws,
                     const float* __restrict__ Wr,
                     const float* __restrict__ Wqr,
                     const float* __restrict__ bqr,
                     const float* __restrict__ Wh,
                     float* __restrict__ subrows,
                     float* __restrict__ hrWr,
                     float* __restrict__ relaWh,
                     float* __restrict__ hqrWqr,
                     int N, int NR, int B, int nA, int nB) {
    __shared__ float lht[128 * 64];    // transposed source tile [d][row]
    const int t = threadIdx.x;
    const int bid = blockIdx.x;
    int type, rbase, nrows;
    const float* src;
    if (bid < nA)           { type = 0; rbase = bid * 64;             nrows = N;  src = hidden; }
    else if (bid < nA + nB) { type = 1; rbase = (bid - nA) * 64;      nrows = NR; src = rela; }
    else                    { type = 2; rbase = (bid - nA - nB) * 64; nrows = B;  src = rela; }

    // stage source tile (transposed)
    const int row = t & 63;
    const int d0 = (t >> 6) * 32;
    const int gr = rbase + row;
    const float* srow = nullptr;
    if (gr < nrows) {
        const int sr = (type == 2) ? q_rel[gr] : gr;
        srow = src + (long)sr * DD;
    }
    #pragma unroll
    for (int j = 0; j < 8; ++j) {
        float4 v = make_float4(0.f, 0.f, 0.f, 0.f);
        if (srow) v = *(const float4*)&srow[d0 + j * 4];
        lht[(d0 + j * 4 + 0) * 64 + row] = v.x;
        lht[(d0 + j * 4 + 1) * 64 + row] = v.y;
        lht[(d0 + j * 4 + 2) * 64 + row] = v.z;
        lht[(d0 + j * 4 + 3) * 64 + row] = v.w;
    }
    __syncthreads();

    const int r0 = (t & 15) * 4;
    const int c0 = (t >> 4) * 4;
    const int nph = (type == 2) ? 1 : 3;

    for (int p = 0; p < nph; ++p) {
        const float* W;
        int ldw, off;
        if (p == 0) {
            W = (type == 0) ? Ws : (type == 1) ? Wr : Wqr;
            ldw = 64; off = 0;
        } else {
            W = Wh; ldw = 128; off = (p - 1) * 64;
        }
        const float* wp = W + off + c0;

        float acc[4][4] = {};
        #pragma unroll 4
        for (int d = 0; d < 128; ++d) {
            const float4 hv = *(const float4*)&lht[d * 64 + r0];
            const float4 wv = *(const float4*)&wp[(long)d * ldw];
            acc[0][0] = fmaf(hv.x, wv.x, acc[0][0]);
            acc[0][1] = fmaf(hv.x, wv.y, acc[0][1]);
            acc[0][2] = fmaf(hv.x, wv.z, acc[0][2]);
            acc[0][3] = fmaf(hv.x, wv.w, acc[0][3]);
            acc[1][0] = fmaf(hv.y, wv.x, acc[1][0]);
            acc[1][1] = fmaf(hv.y, wv.y, acc[1][1]);
            acc[1][2] = fmaf(hv.y, wv.z, acc[1][2]);
            acc[1][3] = fmaf(hv.y, wv.w, acc[1][3]);
            acc[2][0] = fmaf(hv.z, wv.x, acc[2][0]);
            acc[2][1] = fmaf(hv.z, wv.y, acc[2][1]);
            acc[2][2] = fmaf(hv.z, wv.z, acc[2][2]);
            acc[2][3] = fmaf(hv.z, wv.w, acc[2][3]);
            acc[3][0] = fmaf(hv.w, wv.x, acc[3][0]);
            acc[3][1] = fmaf(hv.w, wv.y, acc[3][1]);
            acc[3][2] = fmaf(hv.w, wv.z, acc[3][2]);
            acc[3][3] = fmaf(hv.w, wv.w, acc[3][3]);
        }

        #pragma unroll
        for (int i = 0; i < 4; ++i) {
            const int orow = rbase + r0 + i;
            if (orow >= nrows) continue;
            if (type == 0) {
                float* srw = subrows + (long)orow * SS;
                ushort4 o;
                o.x = f2bf(acc[i][0]); o.y = f2bf(acc[i][1]);
                o.z = f2bf(acc[i][2]); o.w = f2bf(acc[i][3]);
                if (p == 0) {
                    *(ushort4*)((unsigned short*)srw + c0) = o;
                } else {
                    *(ushort4*)((unsigned short*)(srw + 32) + off + c0) = o;
                }
            } else if (type == 1) {
                if (p == 0) {
                    *(float4*)&hrWr[(long)orow * 64 + c0] =
                        make_float4(acc[i][0], acc[i][1], acc[i][2], acc[i][3]);
                } else {
                    *(float4*)&relaWh[(long)orow * 128 + off + c0] =
                        make_float4(acc[i][0], acc[i][1], acc[i][2], acc[i][3]);
                }
            } else {
                const float4 bq = *(const float4*)&bqr[c0];
                *(float4*)&hqrWqr[(long)orow * 64 + c0] =
                    make_float4(acc[i][0] + bq.x, acc[i][1] + bq.y,
                                acc[i][2] + bq.z, acc[i][3] + bq.w);
            }
        }
    }
}

// ---------- histogram of obj ----------
__global__ void hist_kernel(const int* __restrict__ edges, int* deg, int E) {
    const int e = blockIdx.x * blockDim.x + threadIdx.x;
    if (e < E) atomicAdd(&deg[edges[(long)e * 6 + 5]], 1);
}

// ---------------------------------------------------------------------------
// One-dispatch scan: each block locally exclusive-scans its 1024-chunk of deg
// into loff (and seeds cur), stores the chunk total; the LAST block to finish
// (device-scope done counter) computes the exclusive prefix of chunk totals
// into bsumx. Consumers add bsumx[i>>10] on the fly.
// ---------------------------------------------------------------------------
__global__ __launch_bounds__(256)
void scan_kernel(const int* __restrict__ deg, int* __restrict__ loff,
                 int* __restrict__ cur, int* __restrict__ bsum,
                 int* __restrict__ bsumx, int* __restrict__ done,
                 int n, int nb) {
    __shared__ int tsum[256];
    __shared__ int lastFlag;
    const int t = threadIdx.x;
    const int b = blockIdx.x;
    const int base = b * 1024 + t * 4;
    int v[4];
    int s = 0;
    #pragma unroll
    for (int j = 0; j < 4; ++j) {
        v[j] = (base + j < n) ? deg[base + j] : 0;
        s += v[j];
    }
    tsum[t] = s;
    __syncthreads();
    for (int o = 1; o < 256; o <<= 1) {
        const int x = (t >= o) ? tsum[t - o] : 0;
        __syncthreads();
        tsum[t] += x;
        __syncthreads();
    }
    int run = (t > 0) ? tsum[t - 1] : 0;
    #pragma unroll
    for (int j = 0; j < 4; ++j) {
        if (base + j < n) { loff[base + j] = run; cur[base + j] = run; }
        run += v[j];
    }
    if (t == 255) {
        bsum[b] = tsum[255];
        __threadfence();
    }
    __syncthreads();
    if (t == 0) lastFlag = (atomicAdd(done, 1) == nb - 1);
    __syncthreads();
    if (lastFlag && t < 64) {
        __threadfence();
        const int val = (t < nb) ? bsum[t] : 0;
        int inc = val;
        #pragma unroll
        for (int o = 1; o < 64; o <<= 1) {
            const int x = __shfl_up(inc, o, 64);
            if (t >= o) inc += x;
        }
        if (t < nb) bsumx[t] = inc - val;
    }
}

// pack (sub, rel | ridx<<16) bucketed by obj; cur holds LOCAL offsets,
// global position = bsumx[obj>>10] + local rank.
__global__ void scatter_kernel(const int* __restrict__ edges, int* cur,
                               const int* __restrict__ bsumx,
                               int2* __restrict__ recs, int E) {
    const int e = blockIdx.x * blockDim.x + threadIdx.x;
    if (e >= E) return;
    const int2 a = *(const int2*)&edges[(long)e * 6];      // ridx, _
    const int2 b = *(const int2*)&edges[(long)e * 6 + 2];  // rel, _
    const int2 c = *(const int2*)&edges[(long)e * 6 + 4];  // sub, obj
    const int pos = bsumx[c.y >> 10] + atomicAdd(&cur[c.y], 1);
    recs[pos] = make_int2(c.x, b.x | (a.x << 16));
}

// ---------------------------------------------------------------------------
// Gather: one wave per destination node, 16 lanes per edge, 8 edges in flight.
// out[v] = sum_e alpha_e * (hiddenWh[sub] + relaWh[rel]); hiddenWh is bf16
// inside subrows, relaWh is f32 (L2-resident).
// ---------------------------------------------------------------------------
__global__ __launch_bounds__(256)
void gather_kernel(const int2* __restrict__ recs,
                   const int* __restrict__ loff,
                   const int* __restrict__ bsumx,
                   const float* __restrict__ subrows,
                   const float* __restrict__ hrWr,
                   const float* __restrict__ hqrWqr,
                   const float* __restrict__ relaWh,
                   const float* __restrict__ wa,
                   const float* __restrict__ ba,
                   float* __restrict__ out, int N, int E) {
    const int lane = threadIdx.x & 63;
    const int g = lane >> 4;      // edge-group 0..3
    const int l = lane & 15;      // lane within group
    const int v = (int)((blockIdx.x * blockDim.x + threadIdx.x) >> 6);
    if (v >= N) return;
    const float4 wav = *(const float4*)&wa[l * 4];
    const float bar = ba[0];
    const int start = loff[v] + bsumx[v >> 10];
    const int end = (v + 1 < N) ? (loff[v + 1] + bsumx[(v + 1) >> 10]) : E;

    float4 acc0 = make_float4(0.f, 0.f, 0.f, 0.f);
    float4 acc1 = make_float4(0.f, 0.f, 0.f, 0.f);

    for (int base = start; base < end; base += 8) {
        const int k1 = base + g;
        const int k2 = base + 4 + g;
        const bool va1 = (k1 < end);
        const bool va2 = (k2 < end);
        const int2 rc1 = va1 ? recs[k1] : make_int2(0, 0);
        const int2 rc2 = va2 ? recs[k2] : make_int2(0, 0);
        const int sub1 = rc1.x, rel1 = rc1.y & 0xffff, rid1 = rc1.y >> 16;
        const int sub2 = rc2.x, rel2 = rc2.y & 0xffff, rid2 = rc2.y >> 16;
        const float* sr1 = subrows + (long)sub1 * SS;
        const float* sr2 = subrows + (long)sub2 * SS;

        // issue all gathers up front (deep MLP)
        const ushort4 hw1 = *(const ushort4*)((const unsigned short*)sr1 + l * 4);
        const ushort4 hw2 = *(const ushort4*)((const unsigned short*)sr2 + l * 4);
        const float4 b41 = *(const float4*)&hrWr[rel1 * AA + l * 4];
        const float4 b42 = *(const float4*)&hrWr[rel2 * AA + l * 4];
        const float4 c41 = *(const float4*)&hqrWqr[rid1 * AA + l * 4];
        const float4 c42 = *(const float4*)&hqrWqr[rid2 * AA + l * 4];
        const ushort4 m01 = *(const ushort4*)((const unsigned short*)(sr1 + 32) + l * 8);
        const ushort4 m11 = *(const ushort4*)((const unsigned short*)(sr1 + 32) + l * 8 + 4);
        const ushort4 m02 = *(const ushort4*)((const unsigned short*)(sr2 + 32) + l * 8);
        const ushort4 m12 = *(const ushort4*)((const unsigned short*)(sr2 + 32) + l * 8 + 4);
        const float4 r01 = *(const float4*)&relaWh[rel1 * DD + l * 8];
        const float4 r11 = *(const float4*)&relaWh[rel1 * DD + l * 8 + 4];
        const float4 r02 = *(const float4*)&relaWh[rel2 * DD + l * 8];
        const float4 r12 = *(const float4*)&relaWh[rel2 * DD + l * 8 + 4];

        float s1 = fmaxf(bf2f(hw1.x) + b41.x + c41.x, 0.f) * wav.x;
        s1 = fmaf(fmaxf(bf2f(hw1.y) + b41.y + c41.y, 0.f), wav.y, s1);
        s1 = fmaf(fmaxf(bf2f(hw1.z) + b41.z + c41.z, 0.f), wav.z, s1);
        s1 = fmaf(fmaxf(bf2f(hw1.w) + b41.w + c41.w, 0.f), wav.w, s1);
        float s2 = fmaxf(bf2f(hw2.x) + b42.x + c42.x, 0.f) * wav.x;
        s2 = fmaf(fmaxf(bf2f(hw2.y) + b42.y + c42.y, 0.f), wav.y, s2);
        s2 = fmaf(fmaxf(bf2f(hw2.z) + b42.z + c42.z, 0.f), wav.z, s2);
        s2 = fmaf(fmaxf(bf2f(hw2.w) + b42.w + c42.w, 0.f), wav.w, s2);
        s1 += __shfl_xor(s1, 1);  s2 += __shfl_xor(s2, 1);
        s1 += __shfl_xor(s1, 2);  s2 += __shfl_xor(s2, 2);
        s1 += __shfl_xor(s1, 4);  s2 += __shfl_xor(s2, 4);
        s1 += __shfl_xor(s1, 8);  s2 += __shfl_xor(s2, 8);
        float al1 = __builtin_amdgcn_rcpf(1.0f + __expf(-(s1 + bar)));
        float al2 = __builtin_amdgcn_rcpf(1.0f + __expf(-(s2 + bar)));
        if (!va1) al1 = 0.0f;
        if (!va2) al2 = 0.0f;

        acc0.x = fmaf(al1, bf2f(m01.x) + r01.x, acc0.x);
        acc0.y = fmaf(al1, bf2f(m01.y) + r01.y, acc0.y);
        acc0.z = fmaf(al1, bf2f(m01.z) + r01.z, acc0.z);
        acc0.w = fmaf(al1, bf2f(m01.w) + r01.w, acc0.w);
        acc1.x = fmaf(al1, bf2f(m11.x) + r11.x, acc1.x);
        acc1.y = fmaf(al1, bf2f(m11.y) + r11.y, acc1.y);
        acc1.z = fmaf(al1, bf2f(m11.z) + r11.z, acc1.z);
        acc1.w = fmaf(al1, bf2f(m11.w) + r11.w, acc1.w);
        acc0.x = fmaf(al2, bf2f(m02.x) + r02.x, acc0.x);
        acc0.y = fmaf(al2, bf2f(m02.y) + r02.y, acc0.y);
        acc0.z = fmaf(al2, bf2f(m02.z) + r02.z, acc0.z);
        acc0.w = fmaf(al2, bf2f(m02.w) + r02.w, acc0.w);
        acc1.x = fmaf(al2, bf2f(m12.x) + r12.x, acc1.x);
        acc1.y = fmaf(al2, bf2f(m12.y) + r12.y, acc1.y);
        acc1.z = fmaf(al2, bf2f(m12.z) + r12.z, acc1.z);
        acc1.w = fmaf(al2, bf2f(m12.w) + r12.w, acc1.w);
    }

    // combine the 4 edge-groups
    #pragma unroll
    for (int o = 16; o <= 32; o <<= 1) {
        acc0.x += __shfl_xor(acc0.x, o);
        acc0.y += __shfl_xor(acc0.y, o);
        acc0.z += __shfl_xor(acc0.z, o);
        acc0.w += __shfl_xor(acc0.w, o);
        acc1.x += __shfl_xor(acc1.x, o);
        acc1.y += __shfl_xor(acc1.y, o);
        acc1.z += __shfl_xor(acc1.z, o);
        acc1.w += __shfl_xor(acc1.w, o);
    }
    if (g == 0) {
        *(float4*)&out[(long)v * DD + l * 8]     = acc0;
        *(float4*)&out[(long)v * DD + l * 8 + 4] = acc1;
    }
}

extern "C" void kernel_launch(void* const* d_in, const int* in_sizes, int n_in,
                              void* d_out, int out_size, void* d_ws, size_t ws_size,
                              hipStream_t stream) {
    // inputs: 0 q_sub (unused), 1 q_rel, 2 hidden, 3 edges, 4 n_node,
    //         5 rela_embed, 6 Ws, 7 Wr, 8 Wqr, 9 bqr, 10 wa, 11 ba, 12 Wh
    const int*   q_rel  = (const int*)d_in[1];
    const float* hidden = (const float*)d_in[2];
    const int*   edges  = (const int*)d_in[3];
    const float* rela   = (const float*)d_in[5];
    const float* Ws     = (const float*)d_in[6];
    const float* Wr     = (const float*)d_in[7];
    const float* Wqr    = (const float*)d_in[8];
    const float* bqr    = (const float*)d_in[9];
    const float* wa     = (const float*)d_in[10];
    const float* ba     = (const float*)d_in[11];
    const float* Wh     = (const float*)d_in[12];

    const int B  = in_sizes[1];
    const int N  = in_sizes[2] / DD;
    const int E  = in_sizes[3] / 6;
    const int NR = in_sizes[5] / DD;

    float* out = (float*)d_out;

    // workspace layout
    float* subrows = (float*)d_ws;                         // N x SS (all bf16 payload)
    float* hrWr    = subrows + (size_t)N * SS;             // NR x 64
    float* relaWh  = hrWr + (size_t)NR * AA;               // NR x 128
    float* hqrWqr  = relaWh + (size_t)NR * DD;             // B x 64
    int*   deg     = (int*)(hqrWqr + (size_t)B * AA);      // N
    int*   done    = deg + N;                              // 1 (zeroed with deg)
    int*   cur     = done + 3;                             // N   (pad to 4-int align)
    int*   loff    = cur + N;                              // N
    int*   bsum    = loff + N;                             // 64
    int*   bsumx   = bsum + 64;                            // 64
    int2*  recs    = (int2*)(bsumx + 64);                  // E (int count even -> 8B ok)

    const int nA = idiv_up(N, 64);
    const int nB = idiv_up(NR, 64);
    const int nC = idiv_up(B, 64);
    const int nb = idiv_up(N, 1024);

    hipMemsetAsync(deg, 0, (size_t)(N + 1) * sizeof(int), stream);  // deg + done
    proj_all_kernel<<<nA + nB + nC, 256, 0, stream>>>(
        hidden, rela, q_rel, Ws, Wr, Wqr, bqr, Wh,
        subrows, hrWr, relaWh, hqrWqr, N, NR, B, nA, nB);
    hist_kernel<<<idiv_up(E, 256), 256, 0, stream>>>(edges, deg, E);
    scan_kernel<<<nb, 256, 0, stream>>>(deg, loff, cur, bsum, bsumx, done, N, nb);
    scatter_kernel<<<idiv_up(E, 256), 256, 0, stream>>>(edges, cur, bsumx, recs, E);
    gather_kernel<<<idiv_up(N * 64, 256), 256, 0, stream>>>(
        recs, loff, bsumx, subrows, hrWr, hqrWqr, relaWh, wa, ba, out, N, E);
}